// Round 1
// baseline (48.408 us; speedup 1.0000x reference)
//
#include <hip/hip_runtime.h>

// Floyd-Steinberg halftoning, fused: gray conversion + per-8x8-tile error
// diffusion (transposed orientation, matching reference's swapaxes) + 3-channel
// broadcast + zero-mask + /255.
//
// One thread per 8x8 tile. All tile state in registers (fully unrolled loops,
// compile-time indices only). Wave of 64 threads = 64 consecutive tiles along
// W -> each row-of-8 float4 pair is part of a contiguous 2KB wave read.

#define IMG_H 1024
#define IMG_W 1024
#define NCH   3

__global__ __launch_bounds__(256)
void fs_halftone_kernel(const float* __restrict__ in, float* __restrict__ out,
                        int n_imgs) {
#pragma clang fp contract(off)
    const int tiles_w = IMG_W / 8;                 // 128
    const int tiles_h = IMG_H / 8;                 // 128
    const int tiles_per_img = tiles_w * tiles_h;   // 16384

    int tile = blockIdx.x * blockDim.x + threadIdx.x;
    int b  = tile / tiles_per_img;
    if (b >= n_imgs) return;
    int t  = tile % tiles_per_img;
    int th = t / tiles_w;
    int tw = t % tiles_w;

    const size_t imgstride = (size_t)IMG_H * IMG_W;
    const size_t tile_off  = (size_t)(th * 8) * IMG_W + (size_t)(tw * 8);
    const float* base = in  + (size_t)b * NCH * imgstride + tile_off;
    float*      obase = out + (size_t)b * NCH * imgstride + tile_off;

    // ---- load 3-channel tile, compute gray (exact reference op order) and
    //      per-channel zero masks ----
    float g[64];
    unsigned long long zm0 = 0ull, zm1 = 0ull, zm2 = 0ull;

#pragma unroll
    for (int r = 0; r < 8; ++r) {
        float c0[8], c1[8], c2[8];
        *(float4*)&c0[0] = *(const float4*)(base + 0 * imgstride + (size_t)r * IMG_W);
        *(float4*)&c0[4] = *(const float4*)(base + 0 * imgstride + (size_t)r * IMG_W + 4);
        *(float4*)&c1[0] = *(const float4*)(base + 1 * imgstride + (size_t)r * IMG_W);
        *(float4*)&c1[4] = *(const float4*)(base + 1 * imgstride + (size_t)r * IMG_W + 4);
        *(float4*)&c2[0] = *(const float4*)(base + 2 * imgstride + (size_t)r * IMG_W);
        *(float4*)&c2[4] = *(const float4*)(base + 2 * imgstride + (size_t)r * IMG_W + 4);
#pragma unroll
        for (int c = 0; c < 8; ++c) {
            float s0 = c0[c] * 255.0f;   // scaled = batch * 255
            float s1 = c1[c] * 255.0f;
            float s2 = c2[c] * 255.0f;
            int idx = r * 8 + c;
            if (s0 == 0.0f) zm0 |= 1ull << idx;
            if (s1 == 0.0f) zm1 |= 1ull << idx;
            if (s2 == 0.0f) zm2 |= 1ull << idx;
            // gray = (0.114*s0 + 0.587*s1) + 0.299*s2  -- left-to-right, no FMA
            g[idx] = ((0.114f * s0) + (0.587f * s1)) + (0.299f * s2);
        }
    }

    // ---- Floyd-Steinberg on the TRANSPOSED tile.
    // FS row i == original column i; FS col j == original row j.
    // Output pixel of FS (row i, col j) lands at original (row j, col i).
    float nrow[8];
#pragma unroll
    for (int j = 0; j < 8; ++j) nrow[j] = 0.0f;

    unsigned long long hbits = 0ull;  // bit (j*8+i): halftone==255 at orig (j,i)

#pragma unroll
    for (int i = 0; i < 8; ++i) {          // FS rows (original columns)
        float errs[8];
        float er = 0.0f;                   // err_right carry
#pragma unroll
        for (int j = 0; j < 8; ++j) {      // serial pixel scan (original rows)
            float px  = g[j * 8 + i] + nrow[j];  // row + next_row_err
            float old = px + er;                 // + err_right
            bool  on  = old > 127.0f;
            float nw  = on ? 255.0f : 0.0f;
            float e   = old - nw;
            er = e * 0.4375f;                    // 7/16
            errs[j] = e;
            if (on) hbits |= 1ull << (j * 8 + i);
        }
        // nxt = (5/16)*errs + (3/16)*errs[+1] + (1/16)*errs[-1], left-to-right
#pragma unroll
        for (int j = 0; j < 8; ++j) {
            float en = (j < 7) ? errs[j + 1] : 0.0f;
            float ep = (j > 0) ? errs[j - 1] : 0.0f;
            nrow[j] = ((0.3125f * errs[j]) + (0.1875f * en)) + (0.0625f * ep);
        }
    }

    // ---- write 3 channels: out = (input==0) ? 0 : ht/255  (ht/255 in {0,1})
#pragma unroll
    for (int ch = 0; ch < 3; ++ch) {
        unsigned long long zm = (ch == 0) ? zm0 : ((ch == 1) ? zm1 : zm2);
#pragma unroll
        for (int r = 0; r < 8; ++r) {
            float v[8];
#pragma unroll
            for (int c = 0; c < 8; ++c) {
                int idx = r * 8 + c;
                bool on = (hbits >> idx) & 1ull;
                bool z  = (zm    >> idx) & 1ull;
                v[c] = (on && !z) ? 1.0f : 0.0f;
            }
            *(float4*)(obase + ch * imgstride + (size_t)r * IMG_W)     = *(float4*)&v[0];
            *(float4*)(obase + ch * imgstride + (size_t)r * IMG_W + 4) = *(float4*)&v[4];
        }
    }
}

extern "C" void kernel_launch(void* const* d_in, const int* in_sizes, int n_in,
                              void* d_out, int out_size, void* d_ws, size_t ws_size,
                              hipStream_t stream) {
    const float* in  = (const float*)d_in[0];
    float*       out = (float*)d_out;

    int n_imgs = in_sizes[0] / (NCH * IMG_H * IMG_W);  // 8
    int total_tiles = n_imgs * (IMG_H / 8) * (IMG_W / 8);
    int block = 256;
    int grid = (total_tiles + block - 1) / block;
    fs_halftone_kernel<<<grid, block, 0, stream>>>(in, out, n_imgs);
}

// Round 2
// 42.130 us; speedup vs baseline: 1.1490x; 1.1490x over previous
//
#include <hip/hip_runtime.h>

// Floyd-Steinberg halftoning, fused: gray conversion + per-8x8-tile error
// diffusion (transposed orientation, matching reference's swapaxes) + 3-channel
// broadcast + zero-mask + /255.
//
// One thread per 8x8 tile (131072 tiles -> 512 blocks of 256 -> 2 waves/SIMD,
// grid-capped). Since occupancy is grid-limited, we trade VGPRs for load
// pipelining: __launch_bounds__(256,2) allows ~256 VGPRs, and loads are issued
// in two large batches (ch0+ch1, then ch2) so the wave takes ~2 HBM latencies
// instead of ~12 serialized small-batch waits.

#define IMG_H 1024
#define IMG_W 1024
#define NCH   3

__global__ __launch_bounds__(256, 2)
void fs_halftone_kernel(const float* __restrict__ in, float* __restrict__ out,
                        int n_imgs) {
#pragma clang fp contract(off)
    const int tiles_w = IMG_W / 8;                 // 128
    const int tiles_per_img = tiles_w * (IMG_H / 8);

    int tile = blockIdx.x * blockDim.x + threadIdx.x;
    int b  = tile / tiles_per_img;
    if (b >= n_imgs) return;
    int t  = tile % tiles_per_img;
    int th = t / tiles_w;
    int tw = t % tiles_w;

    const size_t imgstride = (size_t)IMG_H * IMG_W;
    const size_t tile_off  = (size_t)(th * 8) * IMG_W + (size_t)(tw * 8);
    const float* base = in  + (size_t)b * NCH * imgstride + tile_off;
    float*      obase = out + (size_t)b * NCH * imgstride + tile_off;

    // ---- batch 1: issue ALL ch0 + ch1 loads (32 x float4 = 128 VGPRs) ----
    float4 l0[8][2], l1[8][2];
#pragma unroll
    for (int r = 0; r < 8; ++r) {
        l0[r][0] = *(const float4*)(base + 0 * imgstride + (size_t)r * IMG_W);
        l0[r][1] = *(const float4*)(base + 0 * imgstride + (size_t)r * IMG_W + 4);
        l1[r][0] = *(const float4*)(base + 1 * imgstride + (size_t)r * IMG_W);
        l1[r][1] = *(const float4*)(base + 1 * imgstride + (size_t)r * IMG_W + 4);
    }

    // partial gray: p = (0.114*s0) + (0.587*s1); masks for ch0/ch1
    float g[64];
    unsigned long long zm0 = 0ull, zm1 = 0ull, zm2 = 0ull;
#pragma unroll
    for (int r = 0; r < 8; ++r) {
#pragma unroll
        for (int h = 0; h < 2; ++h) {
            const float* a0 = (const float*)&l0[r][h];
            const float* a1 = (const float*)&l1[r][h];
#pragma unroll
            for (int k = 0; k < 4; ++k) {
                int c = h * 4 + k;
                int idx = r * 8 + c;
                float s0 = a0[k] * 255.0f;
                float s1 = a1[k] * 255.0f;
                if (s0 == 0.0f) zm0 |= 1ull << idx;
                if (s1 == 0.0f) zm1 |= 1ull << idx;
                g[idx] = (0.114f * s0) + (0.587f * s1);
            }
        }
    }

    // ---- batch 2: all ch2 loads (16 x float4 = 64 VGPRs) ----
    float4 l2[8][2];
#pragma unroll
    for (int r = 0; r < 8; ++r) {
        l2[r][0] = *(const float4*)(base + 2 * imgstride + (size_t)r * IMG_W);
        l2[r][1] = *(const float4*)(base + 2 * imgstride + (size_t)r * IMG_W + 4);
    }
#pragma unroll
    for (int r = 0; r < 8; ++r) {
#pragma unroll
        for (int h = 0; h < 2; ++h) {
            const float* a2 = (const float*)&l2[r][h];
#pragma unroll
            for (int k = 0; k < 4; ++k) {
                int c = h * 4 + k;
                int idx = r * 8 + c;
                float s2 = a2[k] * 255.0f;
                if (s2 == 0.0f) zm2 |= 1ull << idx;
                g[idx] = g[idx] + (0.299f * s2);   // ((0.114 s0 + 0.587 s1) + 0.299 s2)
            }
        }
    }

    // ---- Floyd-Steinberg on the TRANSPOSED tile.
    // FS row i == original column i; FS col j == original row j.
    float nrow[8];
#pragma unroll
    for (int j = 0; j < 8; ++j) nrow[j] = 0.0f;

    unsigned long long hbits = 0ull;  // bit (j*8+i): halftone==255 at orig (j,i)

#pragma unroll
    for (int i = 0; i < 8; ++i) {          // FS rows (original columns)
        float errs[8];
        float er = 0.0f;                   // err_right carry
#pragma unroll
        for (int j = 0; j < 8; ++j) {      // serial pixel scan (original rows)
            float px  = g[j * 8 + i] + nrow[j];  // row + next_row_err
            float old = px + er;                 // + err_right
            bool  on  = old > 127.0f;
            float nw  = on ? 255.0f : 0.0f;
            float e   = old - nw;
            er = e * 0.4375f;                    // 7/16
            errs[j] = e;
            if (on) hbits |= 1ull << (j * 8 + i);
        }
#pragma unroll
        for (int j = 0; j < 8; ++j) {
            float en = (j < 7) ? errs[j + 1] : 0.0f;
            float ep = (j > 0) ? errs[j - 1] : 0.0f;
            nrow[j] = ((0.3125f * errs[j]) + (0.1875f * en)) + (0.0625f * ep);
        }
    }

    // ---- write 3 channels: out = (input==0) ? 0 : ht/255  (ht/255 in {0,1})
#pragma unroll
    for (int ch = 0; ch < 3; ++ch) {
        unsigned long long zm = (ch == 0) ? zm0 : ((ch == 1) ? zm1 : zm2);
#pragma unroll
        for (int r = 0; r < 8; ++r) {
            float v[8];
#pragma unroll
            for (int c = 0; c < 8; ++c) {
                int idx = r * 8 + c;
                bool on = (hbits >> idx) & 1ull;
                bool z  = (zm    >> idx) & 1ull;
                v[c] = (on && !z) ? 1.0f : 0.0f;
            }
            *(float4*)(obase + ch * imgstride + (size_t)r * IMG_W)     = *(float4*)&v[0];
            *(float4*)(obase + ch * imgstride + (size_t)r * IMG_W + 4) = *(float4*)&v[4];
        }
    }
}

extern "C" void kernel_launch(void* const* d_in, const int* in_sizes, int n_in,
                              void* d_out, int out_size, void* d_ws, size_t ws_size,
                              hipStream_t stream) {
    const float* in  = (const float*)d_in[0];
    float*       out = (float*)d_out;

    int n_imgs = in_sizes[0] / (NCH * IMG_H * IMG_W);  // 8
    int total_tiles = n_imgs * (IMG_H / 8) * (IMG_W / 8);
    int block = 256;
    int grid = (total_tiles + block - 1) / block;
    fs_halftone_kernel<<<grid, block, 0, stream>>>(in, out, n_imgs);
}